// Round 1
// baseline (289.131 us; speedup 1.0000x reference)
//
#include <hip/hip_runtime.h>

// MoE fused forward: out = (relu(x@W1[e]+b1[e])@W2[e]+b2[e]) * exp(min(T, log100))
// N=524288, D=128, H=512, E=8, contiguous expert chunks (65536 tokens each).
// Strategy: pre-kernel converts weights to bf16 TRANSPOSED (k-contiguous) in d_ws;
// fused kernel: BM=64 tokens/block, 8 waves, 16x16x32 bf16 MFMA,
// GEMM1 swapped (D1[h][tok]) so epilogue packs 4 consecutive h per lane -> ds_write_b64,
// GEMM2 with double-buffered W2 chunks via global_load_lds. All LDS XOR-swizzled.

#define CLAMP_MAXV 4.605170185988091f

typedef __attribute__((ext_vector_type(8))) short s16x8;
typedef __attribute__((ext_vector_type(4))) float f32x4;
typedef __attribute__((ext_vector_type(4))) unsigned short u16x4;
typedef __attribute__((ext_vector_type(8))) unsigned short u16x8;

static __device__ __forceinline__ unsigned short f2bf(float f) {
  union { float f; unsigned int u; } v; v.f = f;
  unsigned int r = v.u + 0x7FFFu + ((v.u >> 16) & 1u);  // RNE
  return (unsigned short)(r >> 16);
}

static __device__ __forceinline__ void gll16(const void* src, void* dst) {
  __builtin_amdgcn_global_load_lds((const __attribute__((address_space(1))) void*)src,
                                   (__attribute__((address_space(3))) void*)dst, 16, 0, 0);
}

// ---- pre-kernel: W1[e][d][h] -> w1t[e][h][d] bf16 ; W2[e][h][d] -> w2t[e][d][h] bf16
__global__ void conv_w(const float* __restrict__ W1, const float* __restrict__ W2,
                       unsigned short* __restrict__ w1t, unsigned short* __restrict__ w2t) {
  int idx = blockIdx.x * 256 + threadIdx.x;  // 131072 total
  if (idx < 65536) {
    int h  = idx & 511;
    int d0 = ((idx >> 9) & 15) << 3;
    int e  = idx >> 13;
    const float* src = W1 + ((size_t)e << 16);
    u16x8 v;
#pragma unroll
    for (int j = 0; j < 8; ++j) v[j] = f2bf(src[(size_t)(d0 + j) * 512 + h]);
    *(u16x8*)(w1t + ((((size_t)e << 9) + h) << 7) + d0) = v;
  } else {
    int i2 = idx - 65536;
    int d  = i2 & 127;
    int h0 = ((i2 >> 7) & 63) << 3;
    int e  = i2 >> 13;
    const float* src = W2 + ((size_t)e << 16);
    u16x8 v;
#pragma unroll
    for (int j = 0; j < 8; ++j) v[j] = f2bf(src[(size_t)(h0 + j) * 128 + d]);
    *(u16x8*)(w2t + ((((size_t)e << 7) + d) << 9) + h0) = v;
  }
}

// ---- fused MoE kernel
__global__ __launch_bounds__(512, 2) void moe_fused(
    const float* __restrict__ x,
    const float* __restrict__ b1,
    const float* __restrict__ b2,
    const float* __restrict__ temp,
    const unsigned short* __restrict__ w1t,
    const unsigned short* __restrict__ w2t,
    float* __restrict__ out)
{
  __shared__ __align__(16) char smem[147456];
  char* const xs   = smem;                 // 16 KB  [64 tok][128 d] bf16, swz
  char* const w1s  = smem + 16384;         // 128 KB [512 h][128 d] bf16, swz
  char* const hs   = smem + 16384;         // 64 KB  [64 tok][512 h] bf16 (overlays w1s)
  char* const w2sA = smem + 16384 + 65536; // 32 KB  [128 d][128 h-chunk]
  char* const w2sB = smem + 16384 + 65536 + 32768;

  const int tid  = threadIdx.x;
  const int lane = tid & 63;
  const int wid  = tid >> 6;
  const int l15  = lane & 15;
  const int lg   = lane >> 4;
  const int blk  = blockIdx.x;
  const int e    = blk >> 10;              // 1024 blocks per expert

  const float scale = expf(fminf(temp[0], CLAMP_MAXV));

  // ---- stage x tile (fp32 -> bf16, swizzled)
  const float* xg = x + ((size_t)blk << 13);  // blk*64*128
#pragma unroll
  for (int it = 0; it < 4; ++it) {
    int fidx = (tid + it * 512) << 2;
    f32x4 v = *(const f32x4*)(xg + fidx);
    int row = fidx >> 7;
    int col = fidx & 127;
    unsigned addr = (unsigned)((row << 8) + (col << 1)) ^ (unsigned)((row & 7) << 4);
    u16x4 p;
    p[0] = f2bf(v[0]); p[1] = f2bf(v[1]); p[2] = f2bf(v[2]); p[3] = f2bf(v[3]);
    *(u16x4*)(xs + addr) = p;
  }

  // ---- stage w1t (128 KB) via global_load_lds, source pre-swizzled
  const unsigned short* w1g = w1t + ((size_t)e << 16);
#pragma unroll
  for (int r = 0; r < 16; ++r) {
    int chunk = wid * 16 + r;          // 0..127, 1 KB each (4 rows)
    int row = (chunk << 2) + lg;       // h row
    int c16 = l15 ^ (row & 7);
    gll16(w1g + ((size_t)row << 7) + (c16 << 3), w1s + (chunk << 10));
  }
  __syncthreads();

  // ---- GEMM1 (swapped): D1[h][tok] = sum_d W1[d][h] * x[tok][d]
  const int wr = wid >> 1;             // 0..3 : 128-h block
  const int wc = wid & 1;              // 0..1 : 32-tok block
  f32x4 acc1[8][2];
#pragma unroll
  for (int i = 0; i < 8; ++i)
#pragma unroll
    for (int j = 0; j < 2; ++j) acc1[i][j] = (f32x4){0.f, 0.f, 0.f, 0.f};

  const unsigned swz15 = (unsigned)((l15 & 7) << 4);
  const unsigned hrow0 = (unsigned)(wr * 128 + l15);
  const unsigned trow0 = (unsigned)(wc * 32 + l15);

#pragma unroll
  for (int kk = 0; kk < 4; ++kk) {
    const unsigned dof = (unsigned)((kk * 32 + lg * 8) << 1);
    s16x8 a[8], b[2];
#pragma unroll
    for (int i = 0; i < 8; ++i)
      a[i] = *(const s16x8*)(w1s + ((((hrow0 + i * 16) << 8) + dof) ^ swz15));
#pragma unroll
    for (int j = 0; j < 2; ++j)
      b[j] = *(const s16x8*)(xs + ((((trow0 + j * 16) << 8) + dof) ^ swz15));
#pragma unroll
    for (int i = 0; i < 8; ++i)
#pragma unroll
      for (int j = 0; j < 2; ++j)
        acc1[i][j] = __builtin_amdgcn_mfma_f32_16x16x32_bf16(a[i], b[j], acc1[i][j], 0, 0, 0);
  }
  __syncthreads();   // all reads of w1s/xs done; safe to overlay

  // ---- stage W2 chunk 0 into w2sA (overlaps epilogue below)
  const unsigned short* w2g = w2t + ((size_t)e << 16);
#pragma unroll
  for (int r = 0; r < 4; ++r) {
    int q = (wid << 2) + r;            // 0..31, 1 KB each
    int drow = (q << 2) + lg;
    int c16 = l15 ^ (drow & 7);
    gll16(w2g + ((size_t)drow << 9) + (c16 << 3), w2sA + (q << 10));
  }

  // ---- GEMM1 epilogue: +b1, relu, bf16 pack (4 consecutive h per lane) -> hs
  const float* b1e = b1 + (e << 9);
#pragma unroll
  for (int i = 0; i < 8; ++i) {
    unsigned h0 = (unsigned)(wr * 128 + i * 16 + lg * 4);
    f32x4 bias = *(const f32x4*)(b1e + h0);
#pragma unroll
    for (int j = 0; j < 2; ++j) {
      unsigned tok = trow0 + j * 16;
      u16x4 p;
#pragma unroll
      for (int rr = 0; rr < 4; ++rr)
        p[rr] = f2bf(fmaxf(acc1[i][j][rr] + bias[rr], 0.f));
      unsigned addr = ((tok << 10) + (h0 << 1)) ^ ((tok & 7) << 4);
      *(u16x4*)(hs + addr) = p;
    }
  }
  __syncthreads();   // hs written, chunk0 loaded (barrier drains vmcnt)

  // ---- GEMM2: y[tok][dout] = sum_h hs[tok][h] * W2[h][dout], chunked K with dbuf
  const int wt = wid >> 2;             // 0..1 : 32-tok block
  const int wd = wid & 3;              // 0..3 : 32-d block
  f32x4 acc2[2][2];
#pragma unroll
  for (int i = 0; i < 2; ++i)
#pragma unroll
    for (int j = 0; j < 2; ++j) acc2[i][j] = (f32x4){0.f, 0.f, 0.f, 0.f};

  const unsigned trow2 = (unsigned)(wt * 32 + l15);
  const unsigned drow2 = (unsigned)(wd * 32 + l15);

#pragma unroll
  for (int c = 0; c < 4; ++c) {
    char* cur = (c & 1) ? w2sB : w2sA;
    if (c < 3) {
      char* nxt = (c & 1) ? w2sA : w2sB;
#pragma unroll
      for (int r = 0; r < 4; ++r) {
        int q = (wid << 2) + r;
        int drow = (q << 2) + lg;
        int c16 = l15 ^ (drow & 7);
        gll16(w2g + ((size_t)drow << 9) + ((c + 1) << 7) + (c16 << 3), nxt + (q << 10));
      }
    }
#pragma unroll
    for (int kk = 0; kk < 4; ++kk) {
      unsigned kof = (unsigned)((kk * 32 + lg * 8) << 1);
      s16x8 a[2], b[2];
#pragma unroll
      for (int i = 0; i < 2; ++i)
        a[i] = *(const s16x8*)(hs + ((((trow2 + i * 16) << 10) + (c << 8) + kof) ^ swz15));
#pragma unroll
      for (int j = 0; j < 2; ++j)
        b[j] = *(const s16x8*)(cur + ((((drow2 + j * 16) << 8) + kof) ^ swz15));
#pragma unroll
      for (int i = 0; i < 2; ++i)
#pragma unroll
        for (int j = 0; j < 2; ++j)
          acc2[i][j] = __builtin_amdgcn_mfma_f32_16x16x32_bf16(a[i], b[j], acc2[i][j], 0, 0, 0);
    }
    if (c < 3) __syncthreads();
  }

  // ---- GEMM2 epilogue: +b2, scale, fp32 store
  const float* b2e = b2 + (e << 7);
  float* og = out + ((size_t)blk << 13);
#pragma unroll
  for (int j = 0; j < 2; ++j) {
    unsigned d = drow2 + j * 16;
    float bias = b2e[d];
#pragma unroll
    for (int i = 0; i < 2; ++i) {
#pragma unroll
      for (int rr = 0; rr < 4; ++rr) {
        unsigned tok = (unsigned)(wt * 32 + i * 16 + lg * 4 + rr);
        og[((size_t)tok << 7) + d] = (acc2[i][j][rr] + bias) * scale;
      }
    }
  }
}

// ---- fallback (only if ws_size is tiny): naive but correct
__global__ void moe_naive(const float* __restrict__ x, const float* __restrict__ W1,
                          const float* __restrict__ b1, const float* __restrict__ W2,
                          const float* __restrict__ b2, const float* __restrict__ temp,
                          float* __restrict__ out) {
  __shared__ float xr[128];
  __shared__ float hrow[512];
  int t = blockIdx.x;
  int e = t >> 16;
  int tx = threadIdx.x;
  xr[tx] = x[((size_t)t << 7) + tx];
  __syncthreads();
  const float* w1e = W1 + ((size_t)e << 16);
  for (int h = tx; h < 512; h += 128) {
    float s = b1[(e << 9) + h];
    for (int d = 0; d < 128; ++d) s += xr[d] * w1e[(size_t)d * 512 + h];
    hrow[h] = fmaxf(s, 0.f);
  }
  __syncthreads();
  const float* w2e = W2 + ((size_t)e << 16);
  float s = b2[(e << 7) + tx];
  for (int h = 0; h < 512; ++h) s += hrow[h] * w2e[(size_t)h * 128 + tx];
  out[((size_t)t << 7) + tx] = s * expf(fminf(temp[0], CLAMP_MAXV));
}

extern "C" void kernel_launch(void* const* d_in, const int* in_sizes, int n_in,
                              void* d_out, int out_size, void* d_ws, size_t ws_size,
                              hipStream_t stream) {
  const float* x    = (const float*)d_in[0];
  const float* W1   = (const float*)d_in[1];
  const float* b1   = (const float*)d_in[2];
  const float* W2   = (const float*)d_in[3];
  const float* b2   = (const float*)d_in[4];
  const float* temp = (const float*)d_in[5];
  float* out = (float*)d_out;

  const size_t WS_NEEDED = 2u * 524288u * sizeof(unsigned short);  // 2 MB
  if (ws_size >= WS_NEEDED) {
    unsigned short* w1t = (unsigned short*)d_ws;
    unsigned short* w2t = w1t + 524288;
    conv_w<<<512, 256, 0, stream>>>(W1, W2, w1t, w2t);
    moe_fused<<<8192, 512, 0, stream>>>(x, b1, b2, temp, w1t, w2t, out);
  } else {
    moe_naive<<<524288, 128, 0, stream>>>(x, W1, b1, W2, b2, temp, out);
  }
}

// Round 3
// 219.000 us; speedup vs baseline: 1.3202x; 1.3202x over previous
//
#include <hip/hip_runtime.h>

// MoE fused forward: out = (relu(x@W1[e]+b1[e])@W2[e]+b2[e]) * exp(min(T, log100))
// N=524288, D=128, H=512, E=8, contiguous expert chunks.
// R3: R2's interleaved 8-chunk pipeline (GEMM1 chunk -> hsb -> GEMM2 partial),
// but ALL barriers are __syncthreads() (full vmcnt+lgkmcnt drain) — the R2
// counted-vmcnt schedule raced (spill traffic perturbs hand-counted vmcnt;
// single-buffered w2b/hsb had in-flight-read-across-barrier hazards).
// Overlap source: 2 blocks/CU (LDS 74KB) + issue-early gll16 staging.

#define CLAMP_MAXV 4.605170185988091f

typedef __attribute__((ext_vector_type(8))) short s16x8;
typedef __attribute__((ext_vector_type(4))) float f32x4;
typedef __attribute__((ext_vector_type(4))) unsigned short u16x4;
typedef __attribute__((ext_vector_type(8))) unsigned short u16x8;

static __device__ __forceinline__ unsigned short f2bf(float f) {
  union { float f; unsigned int u; } v; v.f = f;
  unsigned int r = v.u + 0x7FFFu + ((v.u >> 16) & 1u);  // RNE
  return (unsigned short)(r >> 16);
}

static __device__ __forceinline__ void gll16(const void* src, void* dst) {
  __builtin_amdgcn_global_load_lds((const __attribute__((address_space(1))) void*)src,
                                   (__attribute__((address_space(3))) void*)dst, 16, 0, 0);
}

// ---- pre-kernel: W1[e][d][h] -> w1t[e][h][d] bf16 ; W2[e][h][d] -> w2t[e][d][h] bf16
__global__ void conv_w(const float* __restrict__ W1, const float* __restrict__ W2,
                       unsigned short* __restrict__ w1t, unsigned short* __restrict__ w2t) {
  int idx = blockIdx.x * 256 + threadIdx.x;  // 131072 total
  if (idx < 65536) {
    int h  = idx & 511;
    int d0 = ((idx >> 9) & 15) << 3;
    int e  = idx >> 13;
    const float* src = W1 + ((size_t)e << 16);
    u16x8 v;
#pragma unroll
    for (int j = 0; j < 8; ++j) v[j] = f2bf(src[(size_t)(d0 + j) * 512 + h]);
    *(u16x8*)(w1t + ((((size_t)e << 9) + h) << 7) + d0) = v;
  } else {
    int i2 = idx - 65536;
    int d  = i2 & 127;
    int h0 = ((i2 >> 7) & 63) << 3;
    int e  = i2 >> 13;
    const float* src = W2 + ((size_t)e << 16);
    u16x8 v;
#pragma unroll
    for (int j = 0; j < 8; ++j) v[j] = f2bf(src[(size_t)(h0 + j) * 128 + d]);
    *(u16x8*)(w2t + ((((size_t)e << 7) + d) << 9) + h0) = v;
  }
}

// ---- fused MoE kernel
__global__ __launch_bounds__(512, 4) void moe_fused(
    const float* __restrict__ x,
    const float* __restrict__ b1,
    const float* __restrict__ b2,
    const float* __restrict__ temp,
    const unsigned short* __restrict__ w1t,
    const unsigned short* __restrict__ w2t,
    float* __restrict__ out)
{
  __shared__ __align__(16) char smem[75776];
  char* const xs   = smem;            // 16 KB [64 tok][128 d] bf16, swz ^((tok&7)<<4)
  char* const w1b0 = smem + 16384;    // 16 KB [64 h][128 d] bf16, swz ^((h&7)<<4)
  char* const w1b1 = smem + 32768;    // 16 KB
  char* const w2b  = smem + 49152;    // 16 KB [128 d][64 h] bf16, swz ^((d&7)<<4)
  char* const hsb  = smem + 65536;    //  8 KB [64 tok][64 h] bf16, swz ^((tok&7)<<4)
  float* const b1s = (float*)(smem + 73728);  // 2 KB, 512 f32

  const int tid  = threadIdx.x;
  const int lane = tid & 63;
  const int wid  = tid >> 6;
  const int l15  = lane & 15;
  const int lg   = lane >> 4;
  const int blk  = blockIdx.x;
  const int e    = blk >> 10;                 // 1024 blocks per expert

  // GEMM1 wave map: hr = 16-h row, tq0 = token-half base
  const int hr  = wid & 3;
  const int tq0 = (wid >> 2) << 5;            // 0 or 32
  // GEMM2 wave map: tb = 16-tok row, db = 64-d half
  const int tb  = wid & 3;
  const int db  = wid >> 2;

  const unsigned short* w1g = w1t + ((size_t)e << 16);
  const unsigned short* w2g = w2t + ((size_t)e << 16);

  // ---- prologue loads (issue HBM x first, then L2 weights)
  const float* xg = x + ((size_t)blk << 13);  // blk*64*128
  f32x4 xv[4];
#pragma unroll
  for (int it = 0; it < 4; ++it)
    xv[it] = *(const f32x4*)(xg + ((tid + it * 512) << 2));
  const float b1v   = b1[(e << 9) + tid];
  const float scale = expf(fminf(temp[0], CLAMP_MAXV));

  // issue w1 chunk0 and w2 chunk0 (2 gll16 each per thread)
#pragma unroll
  for (int k = 0; k < 2; ++k) {
    int s = tid + (k << 9);                   // 0..1023 slots of 16B
    int hloc = s >> 4, sr = s & 15;
    gll16(w1g + ((size_t)hloc << 7) + ((sr ^ (hloc & 7)) << 3), w1b0 + (s << 4));
  }
#pragma unroll
  for (int k = 0; k < 2; ++k) {
    int s = tid + (k << 9);
    int d = s >> 3, sr = s & 7;
    gll16(w2g + ((size_t)d << 9) + ((sr ^ (d & 7)) << 3), w2b + (s << 4));
  }

  // write xs (fp32 -> bf16, swizzled)
#pragma unroll
  for (int it = 0; it < 4; ++it) {
    int idx = (tid + it * 512) << 2;
    int t = idx >> 7, dcol = idx & 127;
    unsigned addr = (unsigned)((t << 8) + (dcol << 1)) ^ (unsigned)((t & 7) << 4);
    u16x4 p;
    p[0] = f2bf(xv[it][0]); p[1] = f2bf(xv[it][1]);
    p[2] = f2bf(xv[it][2]); p[3] = f2bf(xv[it][3]);
    *(u16x4*)(xs + addr) = p;
  }
  b1s[tid] = b1v;

  __syncthreads();

  // ---- hoist x fragments to registers (reused by all 8 chunks)
  s16x8 xb[2][4];
#pragma unroll
  for (int j = 0; j < 2; ++j) {
    int tok = tq0 + (j << 4) + l15;
#pragma unroll
    for (int ks = 0; ks < 4; ++ks) {
      unsigned koff = (unsigned)((ks * 32 + lg * 8) << 1);
      xb[j][ks] = *(const s16x8*)(xs + (((unsigned)(tok << 8) + koff) ^ (unsigned)((tok & 7) << 4)));
    }
  }

  f32x4 acc2[4];
#pragma unroll
  for (int j = 0; j < 4; ++j) acc2[j] = (f32x4){0.f, 0.f, 0.f, 0.f};

  const int hrow = hr * 16 + l15;
  const unsigned hswz = (unsigned)((hrow & 7) << 4);
  const int tokr = tb * 16 + l15;
  const unsigned tswz = (unsigned)((tokr & 7) << 4);

  // ---- main loop: 8 chunks of 64 h
#pragma unroll
  for (int c = 0; c < 8; ++c) {
    char* const w1cur = (c & 1) ? w1b1 : w1b0;
    char* const w1nxt = (c & 1) ? w1b0 : w1b1;

    // issue w2_c (c>0; c==0 issued in prologue), then w1_{c+1}
    if (c > 0) {
#pragma unroll
      for (int k = 0; k < 2; ++k) {
        int s = tid + (k << 9);
        int d = s >> 3, sr = s & 7;
        gll16(w2g + ((size_t)d << 9) + (c << 6) + ((sr ^ (d & 7)) << 3), w2b + (s << 4));
      }
    }
    if (c < 7) {
#pragma unroll
      for (int k = 0; k < 2; ++k) {
        int s = tid + (k << 9);
        int hloc = s >> 4, sr = s & 15;
        gll16(w1g + ((size_t)((c + 1) * 64 + hloc) << 7) + ((sr ^ (hloc & 7)) << 3),
              w1nxt + (s << 4));
      }
    }

    // ---- GEMM1 chunk c: D1[h][tok] = sum_d W1[d][h]*x[tok][d]
    s16x8 a[4];
#pragma unroll
    for (int ks = 0; ks < 4; ++ks) {
      unsigned koff = (unsigned)((ks * 32 + lg * 8) << 1);
      a[ks] = *(const s16x8*)(w1cur + (((unsigned)(hrow << 8) + koff) ^ hswz));
    }
    f32x4 acc1[2];
    acc1[0] = (f32x4){0.f, 0.f, 0.f, 0.f};
    acc1[1] = (f32x4){0.f, 0.f, 0.f, 0.f};
#pragma unroll
    for (int j = 0; j < 2; ++j)
#pragma unroll
      for (int ks = 0; ks < 4; ++ks)
        acc1[j] = __builtin_amdgcn_mfma_f32_16x16x32_bf16(a[ks], xb[j][ks], acc1[j], 0, 0, 0);

    // epilogue: +b1, relu, pack -> hs
    f32x4 bias = *(const f32x4*)(b1s + c * 64 + hr * 16 + lg * 4);
    const unsigned hl2 = (unsigned)((hr * 16 + lg * 4) << 1);
#pragma unroll
    for (int j = 0; j < 2; ++j) {
      int tok = tq0 + (j << 4) + l15;
      u16x4 p;
#pragma unroll
      for (int r = 0; r < 4; ++r)
        p[r] = f2bf(fmaxf(acc1[j][r] + bias[r], 0.f));
      *(u16x4*)(hsb + (((unsigned)(tok << 7) + hl2) ^ (unsigned)((tok & 7) << 4))) = p;
    }

    // B1: full drain — hs visible, w2_c (and w1_{c+1}) landed
    __syncthreads();

    // ---- GEMM2 chunk c: acc2[tok][d] += hs[tok][k] * W2t[d][k]
    s16x8 ha[2];
#pragma unroll
    for (int ks = 0; ks < 2; ++ks) {
      unsigned koff = (unsigned)((ks * 32 + lg * 8) << 1);
      ha[ks] = *(const s16x8*)(hsb + (((unsigned)(tokr << 7) + koff) ^ tswz));
    }
#pragma unroll
    for (int j = 0; j < 4; ++j) {
      int drow = db * 64 + j * 16 + l15;
      unsigned dswz = (unsigned)((drow & 7) << 4);
#pragma unroll
      for (int ks = 0; ks < 2; ++ks) {
        unsigned koff = (unsigned)((ks * 32 + lg * 8) << 1);
        s16x8 wb = *(const s16x8*)(w2b + (((unsigned)(drow << 7) + koff) ^ dswz));
        acc2[j] = __builtin_amdgcn_mfma_f32_16x16x32_bf16(ha[ks], wb, acc2[j], 0, 0, 0);
      }
    }

    // B2: full drain — all GEMM2 reads of hsb/w2b complete before next overwrite
    if (c < 7) __syncthreads();
  }

  // ---- epilogue: +b2, scale, fp32 store
  const float* b2e = b2 + (e << 7);
  float* og = out + ((size_t)blk << 13);
#pragma unroll
  for (int j = 0; j < 4; ++j) {
    int d = db * 64 + j * 16 + l15;
    float bv = b2e[d];
#pragma unroll
    for (int r = 0; r < 4; ++r) {
      int t = tb * 16 + lg * 4 + r;
      og[((size_t)t << 7) + d] = (acc2[j][r] + bv) * scale;
    }
  }
}

// ---- fallback (only if ws_size is tiny): naive but correct
__global__ void moe_naive(const float* __restrict__ x, const float* __restrict__ W1,
                          const float* __restrict__ b1, const float* __restrict__ W2,
                          const float* __restrict__ b2, const float* __restrict__ temp,
                          float* __restrict__ out) {
  __shared__ float xr[128];
  __shared__ float hrow[512];
  int t = blockIdx.x;
  int e = t >> 16;
  int tx = threadIdx.x;
  xr[tx] = x[((size_t)t << 7) + tx];
  __syncthreads();
  const float* w1e = W1 + ((size_t)e << 16);
  for (int h = tx; h < 512; h += 128) {
    float s = b1[(e << 9) + h];
    for (int d = 0; d < 128; ++d) s += xr[d] * w1e[(size_t)d * 512 + h];
    hrow[h] = fmaxf(s, 0.f);
  }
  __syncthreads();
  const float* w2e = W2 + ((size_t)e << 16);
  float s = b2[(e << 7) + tx];
  for (int h = 0; h < 512; ++h) s += hrow[h] * w2e[(size_t)h * 128 + tx];
  out[((size_t)t << 7) + tx] = s * expf(fminf(temp[0], CLAMP_MAXV));
}

extern "C" void kernel_launch(void* const* d_in, const int* in_sizes, int n_in,
                              void* d_out, int out_size, void* d_ws, size_t ws_size,
                              hipStream_t stream) {
  const float* x    = (const float*)d_in[0];
  const float* W1   = (const float*)d_in[1];
  const float* b1   = (const float*)d_in[2];
  const float* W2   = (const float*)d_in[3];
  const float* b2   = (const float*)d_in[4];
  const float* temp = (const float*)d_in[5];
  float* out = (float*)d_out;

  const size_t WS_NEEDED = 2u * 524288u * sizeof(unsigned short);  // 2 MB
  if (ws_size >= WS_NEEDED) {
    unsigned short* w1t = (unsigned short*)d_ws;
    unsigned short* w2t = w1t + 524288;
    conv_w<<<512, 256, 0, stream>>>(W1, W2, w1t, w2t);
    moe_fused<<<8192, 512, 0, stream>>>(x, b1, b2, temp, w1t, w2t, out);
  } else {
    moe_naive<<<524288, 128, 0, stream>>>(x, W1, b1, W2, b2, temp, out);
  }
}

// Round 4
// 193.555 us; speedup vs baseline: 1.4938x; 1.1315x over previous
//
#include <hip/hip_runtime.h>

// MoE fused forward: out = (relu(x@W1[e]+b1[e])@W2[e]+b2[e]) * exp(min(T, log100))
// N=524288, D=128, H=512, E=8, contiguous expert chunks.
// R4: weight-RESIDENT blocks. 1024 blocks (1/CU), each owns expert blk>>7 and
// 8 token-tiles of 64. w1 (128KB) staged to LDS once/block; w2 in VGPRs
// (64/wave, wave owns a 16-d slice); per tile a 9-interval pipeline
// GEMM1(c)->hsb[c&1] || GEMM2(c-1)<-hsb[(c-1)&1], one raw lgkm barrier per
// interval (no vmcnt drain -> next-tile x prefetch stays in flight, T14).

#define CLAMP_MAXV 4.605170185988091f

typedef __attribute__((ext_vector_type(8))) short s16x8;
typedef __attribute__((ext_vector_type(4))) float f32x4;
typedef __attribute__((ext_vector_type(4))) unsigned short u16x4;
typedef __attribute__((ext_vector_type(8))) unsigned short u16x8;

static __device__ __forceinline__ unsigned short f2bf(float f) {
  union { float f; unsigned int u; } v; v.f = f;
  unsigned int r = v.u + 0x7FFFu + ((v.u >> 16) & 1u);  // RNE
  return (unsigned short)(r >> 16);
}

static __device__ __forceinline__ void gll16(const void* src, void* dst) {
  __builtin_amdgcn_global_load_lds((const __attribute__((address_space(1))) void*)src,
                                   (__attribute__((address_space(3))) void*)dst, 16, 0, 0);
}

// LDS-only barrier: own-wave lgkm drain + s_barrier; does NOT drain vmcnt, so
// global prefetch loads stay in flight. All cross-wave hazards here are LDS.
#define LBAR() do { \
  asm volatile("s_waitcnt lgkmcnt(0)" ::: "memory"); \
  __builtin_amdgcn_s_barrier(); \
  __builtin_amdgcn_sched_barrier(0); \
} while (0)

// ---- pre-kernel: W1[e][d][h] -> w1t[e][h][d] bf16 ; W2[e][h][d] -> w2t[e][d][h] bf16
__global__ void conv_w(const float* __restrict__ W1, const float* __restrict__ W2,
                       unsigned short* __restrict__ w1t, unsigned short* __restrict__ w2t) {
  int idx = blockIdx.x * 256 + threadIdx.x;  // 131072 total
  if (idx < 65536) {
    int h  = idx & 511;
    int d0 = ((idx >> 9) & 15) << 3;
    int e  = idx >> 13;
    const float* src = W1 + ((size_t)e << 16);
    u16x8 v;
#pragma unroll
    for (int j = 0; j < 8; ++j) v[j] = f2bf(src[(size_t)(d0 + j) * 512 + h]);
    *(u16x8*)(w1t + ((((size_t)e << 9) + h) << 7) + d0) = v;
  } else {
    int i2 = idx - 65536;
    int d  = i2 & 127;
    int h0 = ((i2 >> 7) & 63) << 3;
    int e  = i2 >> 13;
    const float* src = W2 + ((size_t)e << 16);
    u16x8 v;
#pragma unroll
    for (int j = 0; j < 8; ++j) v[j] = f2bf(src[(size_t)(h0 + j) * 128 + d]);
    *(u16x8*)(w2t + ((((size_t)e << 7) + d) << 9) + h0) = v;
  }
}

// ---- fused MoE kernel (weight-resident)
__global__ __launch_bounds__(512, 2) void moe_fused(
    const float* __restrict__ x,
    const float* __restrict__ b1,
    const float* __restrict__ b2,
    const float* __restrict__ temp,
    const unsigned short* __restrict__ w1t,
    const unsigned short* __restrict__ w2t,
    float* __restrict__ out)
{
  __shared__ __align__(16) char smem[149504];
  char* const w1s  = smem;                     // 128 KB [512 h][128 d] bf16, swz ^((h&7)<<4)
  char* const hsb0 = smem + 131072;            //   8 KB [64 tok][64 h] bf16, swz ^((tok&7)<<4)
  char* const hsb1 = smem + 139264;            //   8 KB
  char* const xs   = smem + 131072;            //  16 KB [64 tok][128 d] bf16 (aliases hsb0+hsb1)
  float* const b1s = (float*)(smem + 147456);  //   2 KB

  const int tid  = threadIdx.x;
  const int lane = tid & 63;
  const int wid  = tid >> 6;
  const int l15  = lane & 15;
  const int lg   = lane >> 4;
  const int blk  = blockIdx.x;
  const int e     = blk >> 7;                  // 128 blocks per expert
  const int bslot = blk & 127;                 // 512 tokens per block (8 tiles x 64)

  const unsigned short* w1g = w1t + ((size_t)e << 16);
  const unsigned short* w2g = w2t + ((size_t)e << 16);

  // ---- prologue: stage w1 (128 KB) once, source pre-swizzled
#pragma unroll
  for (int k = 0; k < 16; ++k) {
    int s = tid + (k << 9);                    // 0..8191 slots of 16 B
    int h = s >> 4, sr = s & 15;
    gll16(w1g + ((size_t)h << 7) + ((sr ^ (h & 7)) << 3), w1s + (s << 4));
  }

  // ---- w2 fragments to registers: wave owns d-slice [wid*16, wid*16+16)
  const int dlane = (wid << 4) + l15;
  s16x8 w2f[8][2];
#pragma unroll
  for (int c = 0; c < 8; ++c)
#pragma unroll
    for (int ks = 0; ks < 2; ++ks)
      w2f[c][ks] = *(const s16x8*)(w2g + ((size_t)dlane << 9) + (c << 6) + (ks << 5) + (lg << 3));

  b1s[tid] = b1[(e << 9) + tid];
  const float b2v   = b2[(e << 7) + dlane];
  const float scale = expf(fminf(temp[0], CLAMP_MAXV));

  // ---- x tile 0 prefetch
  const float* xbase = x + (((size_t)e << 16) + ((size_t)bslot << 9)) * 128 / 128 * 128;
  const float* xb0   = x + ((((size_t)e << 16) + ((size_t)bslot << 9)) << 7) / 128;
  // (simplify: token base = e*65536 + bslot*512; float base = token*128)
  const float* xg = x + (((size_t)(e << 16) + ((size_t)bslot << 9)) << 7) / 128;
  (void)xbase; (void)xb0; (void)xg;
  const size_t tok0 = ((size_t)e << 16) + ((size_t)bslot << 9);
  const float* xblk = x + (tok0 << 7);
  float* const oblk = out + (tok0 << 7);

  f32x4 xv[4];
#pragma unroll
  for (int it = 0; it < 4; ++it)
    xv[it] = *(const f32x4*)(xblk + ((tid + (it << 9)) << 2));

  __syncthreads();  // full drain: w1s + w2f + b1s ready

  // GEMM1 wave map: hr = 16-h row within 64-chunk, tq0 = 32-token half
  const int hr  = wid & 3;
  const int tq0 = (wid >> 2) << 5;
  const unsigned hl2 = (unsigned)(((hr << 4) + (lg << 2)) << 1);

  // ---- tile loop: 8 tiles of 64 tokens
#pragma unroll 1
  for (int t = 0; t < 8; ++t) {
    // write xs (fp32 -> bf16, swizzled) from prefetched xv
#pragma unroll
    for (int it = 0; it < 4; ++it) {
      int idx = (tid + (it << 9)) << 2;
      int tk = idx >> 7, col = idx & 127;
      unsigned addr = (unsigned)((tk << 8) + (col << 1)) ^ (unsigned)((tk & 7) << 4);
      u16x4 p;
      p[0] = f2bf(xv[it][0]); p[1] = f2bf(xv[it][1]);
      p[2] = f2bf(xv[it][2]); p[3] = f2bf(xv[it][3]);
      *(u16x4*)(xs + addr) = p;
    }
    // issue next tile's x loads (stay in flight across the chunk loop)
    if (t < 7) {
      const float* xn = xblk + (((size_t)t + 1) << 13);
#pragma unroll
      for (int it = 0; it < 4; ++it)
        xv[it] = *(const f32x4*)(xn + ((tid + (it << 9)) << 2));
    }
    LBAR();  // xs visible to all waves (lgkm only)

    // hoist x fragments (wave's 32-token half)
    s16x8 xb[2][4];
#pragma unroll
    for (int j = 0; j < 2; ++j) {
      int tk = tq0 + (j << 4) + l15;
#pragma unroll
      for (int ks = 0; ks < 4; ++ks) {
        unsigned koff = (unsigned)(((ks << 5) + (lg << 3)) << 1);
        xb[j][ks] = *(const s16x8*)(xs + (((unsigned)(tk << 8) + koff) ^ (unsigned)((tk & 7) << 4)));
      }
    }
    LBAR();  // all hoists done before hsb (aliasing xs) is overwritten

    f32x4 acc2[4];
#pragma unroll
    for (int i = 0; i < 4; ++i) acc2[i] = (f32x4){0.f, 0.f, 0.f, 0.f};

    // ---- 9-interval pipeline: GEMM1(c) || GEMM2(c-1)
#pragma unroll
    for (int c = 0; c <= 8; ++c) {
      if (c < 8) {
        // GEMM1 chunk c: D1[h][tok] = sum_d W1[d][h]*x[tok][d], h in [c*64, c*64+64)
        const int hrow = (c << 6) + (hr << 4) + l15;
        const unsigned hswz = (unsigned)((hrow & 7) << 4);
        s16x8 a[4];
#pragma unroll
        for (int ks = 0; ks < 4; ++ks) {
          unsigned koff = (unsigned)(((ks << 5) + (lg << 3)) << 1);
          a[ks] = *(const s16x8*)(w1s + (((unsigned)(hrow << 8) + koff) ^ hswz));
        }
        f32x4 acc1[2];
        acc1[0] = (f32x4){0.f, 0.f, 0.f, 0.f};
        acc1[1] = (f32x4){0.f, 0.f, 0.f, 0.f};
#pragma unroll
        for (int j = 0; j < 2; ++j)
#pragma unroll
          for (int ks = 0; ks < 4; ++ks)
            acc1[j] = __builtin_amdgcn_mfma_f32_16x16x32_bf16(a[ks], xb[j][ks], acc1[j], 0, 0, 0);

        // +b1, relu, pack -> hsb[c&1]
        f32x4 bias = *(const f32x4*)(b1s + (c << 6) + (hr << 4) + (lg << 2));
        char* const hw = (c & 1) ? hsb1 : hsb0;
#pragma unroll
        for (int j = 0; j < 2; ++j) {
          int tk = tq0 + (j << 4) + l15;
          u16x4 p;
#pragma unroll
          for (int r = 0; r < 4; ++r)
            p[r] = f2bf(fmaxf(acc1[j][r] + bias[r], 0.f));
          *(u16x4*)(hw + (((unsigned)(tk << 7) + hl2) ^ (unsigned)((tk & 7) << 4))) = p;
        }
      }
      if (c > 0) {
        // GEMM2 chunk c-1: acc2[tok][dlane] += hs[tok][k] * W2[k][dlane]
        char* const hrd = ((c - 1) & 1) ? hsb1 : hsb0;
#pragma unroll
        for (int i = 0; i < 4; ++i) {
          int tk = (i << 4) + l15;
          unsigned tswz = (unsigned)((tk & 7) << 4);
#pragma unroll
          for (int ks = 0; ks < 2; ++ks) {
            unsigned koff = (unsigned)(((ks << 5) + (lg << 3)) << 1);
            s16x8 ha = *(const s16x8*)(hrd + (((unsigned)(tk << 7) + koff) ^ tswz));
            acc2[i] = __builtin_amdgcn_mfma_f32_16x16x32_bf16(ha, w2f[c - 1][ks], acc2[i], 0, 0, 0);
          }
        }
      }
      LBAR();
    }

    // ---- epilogue: +b2, scale, fp32 store (tile t)
    float* og = oblk + ((size_t)t << 13);
#pragma unroll
    for (int i = 0; i < 4; ++i) {
#pragma unroll
      for (int r = 0; r < 4; ++r) {
        int tk = (i << 4) + (lg << 2) + r;
        og[((size_t)tk << 7) + dlane] = (acc2[i][r] + b2v) * scale;
      }
    }
  }
}

// ---- fallback (only if ws_size is tiny): naive but correct
__global__ void moe_naive(const float* __restrict__ x, const float* __restrict__ W1,
                          const float* __restrict__ b1, const float* __restrict__ W2,
                          const float* __restrict__ b2, const float* __restrict__ temp,
                          float* __restrict__ out) {
  __shared__ float xr[128];
  __shared__ float hrow[512];
  int t = blockIdx.x;
  int e = t >> 16;
  int tx = threadIdx.x;
  xr[tx] = x[((size_t)t << 7) + tx];
  __syncthreads();
  const float* w1e = W1 + ((size_t)e << 16);
  for (int h = tx; h < 512; h += 128) {
    float s = b1[(e << 9) + h];
    for (int d = 0; d < 128; ++d) s += xr[d] * w1e[(size_t)d * 512 + h];
    hrow[h] = fmaxf(s, 0.f);
  }
  __syncthreads();
  const float* w2e = W2 + ((size_t)e << 16);
  float s = b2[(e << 7) + tx];
  for (int h = 0; h < 512; ++h) s += hrow[h] * w2e[(size_t)h * 128 + tx];
  out[((size_t)t << 7) + tx] = s * expf(fminf(temp[0], CLAMP_MAXV));
}

extern "C" void kernel_launch(void* const* d_in, const int* in_sizes, int n_in,
                              void* d_out, int out_size, void* d_ws, size_t ws_size,
                              hipStream_t stream) {
  const float* x    = (const float*)d_in[0];
  const float* W1   = (const float*)d_in[1];
  const float* b1   = (const float*)d_in[2];
  const float* W2   = (const float*)d_in[3];
  const float* b2   = (const float*)d_in[4];
  const float* temp = (const float*)d_in[5];
  float* out = (float*)d_out;

  const size_t WS_NEEDED = 2u * 524288u * sizeof(unsigned short);  // 2 MB
  if (ws_size >= WS_NEEDED) {
    unsigned short* w1t = (unsigned short*)d_ws;
    unsigned short* w2t = w1t + 524288;
    conv_w<<<512, 256, 0, stream>>>(W1, W2, w1t, w2t);
    moe_fused<<<1024, 512, 0, stream>>>(x, b1, b2, temp, w1t, w2t, out);
  } else {
    moe_naive<<<524288, 128, 0, stream>>>(x, W1, b1, W2, b2, temp, out);
  }
}